// Round 2
// baseline (516.896 us; speedup 1.0000x reference)
//
#include <hip/hip_runtime.h>

// QORNN: quantized orthogonal RNN — exact-integer recurrence.
// v2: 4-way K-split across quads + DPP quad-butterfly reduction.
// Round-1 analysis: v1 was LDS-read-pipe bound (80 ds_read_b128/CU/step
// ~ 960cy/step from full-h broadcast to every lane). Now lane l reads only
// k-quarter (l&3) of h (4xb128 instead of 16x) and computes partials for 4
// consecutive outputs; the 4 partials per output sit in one quad and are
// reduced with v_add+DPP quad_perm (VALU pipe, not LDS pipe).

#define TSEQ 1024
#define IDIM 64
#define HDIM 256
#define ODIM 16
#define CHUNK 16
#define NCHUNK (TSEQ / CHUNK)

__device__ __forceinline__ int sdot4i8(int a, int b, int c) {
#if __has_builtin(__builtin_amdgcn_sdot4)
    return __builtin_amdgcn_sdot4(a, b, c, false);
#else
    int r = c;
    r += ((a << 24) >> 24) * ((b << 24) >> 24);
    r += ((a << 16) >> 24) * ((b << 16) >> 24);
    r += ((a << 8)  >> 24) * ((b << 8)  >> 24);
    r += (a >> 24) * (b >> 24);
    return r;
#endif
}

__device__ __forceinline__ int qpack4(float4 f, float s, float lo, float hi) {
    int a = (int)fminf(fmaxf(rintf(f.x * s), lo), hi);
    int b = (int)fminf(fmaxf(rintf(f.y * s), lo), hi);
    int c = (int)fminf(fmaxf(rintf(f.z * s), lo), hi);
    int d = (int)fminf(fmaxf(rintf(f.w * s), lo), hi);
    return (a & 255) | ((b & 255) << 8) | ((c & 255) << 16) | ((d & 255) << 24);
}

// quad butterfly: after this, all 4 lanes of each quad hold the quad-sum
__device__ __forceinline__ int quad_reduce_add(int v) {
    v += __builtin_amdgcn_update_dpp(0, v, 0xB1, 0xF, 0xF, true); // xor 1
    v += __builtin_amdgcn_update_dpp(0, v, 0x4E, 0xF, 0xF, true); // xor 2
    return v;
}

__global__ __launch_bounds__(256, 1)
void qornn_kernel(const float* __restrict__ x, const float* __restrict__ Wi,
                  const float* __restrict__ Wr, const float* __restrict__ Wo,
                  const float* __restrict__ bias, float* __restrict__ out) {
    __shared__ alignas(16) int wstage[8192];   // 32 KB staging (Wi, Wr halves, then Wo resident)
    __shared__ alignas(16) int xbuf[2][256];   // 2 x (16 steps x 64 int8)
    __shared__ alignas(16) int hbuf[2][64];    // 2 x 256 int8

    const int tid = threadIdx.x;
    const int brow = blockIdx.x;
    const int w    = tid >> 6;       // wave id 0..3
    const int l    = tid & 63;
    const int q    = l & 3;          // k-quarter this lane reads
    const int m16  = l >> 2;         // quad id within wave 0..15
    const int obase = w * 64 + m16 * 4;  // 4 outputs: obase..obase+3

    // ---- stage Wi [256 x 64] fp32 -> int8 (scale 8); lane keeps 4 quarter-rows ----
    {
        const float4* wi4 = (const float4*)Wi;
        #pragma unroll
        for (int it = 0; it < 16; ++it) {
            int flat = it * 256 + tid;           // dword idx 0..4095
            wstage[flat] = qpack4(wi4[flat], 8.0f, -8.0f, 7.0f);
        }
    }
    __syncthreads();
    int4 wiq[4];   // wiq[i] = Wi[obase+i][q*16 .. q*16+15] as 16 int8
    {
        const int4* p = (const int4*)wstage;     // row o = 4 int4s
        #pragma unroll
        for (int i = 0; i < 4; ++i) wiq[i] = p[(obase + i) * 4 + q];
    }
    __syncthreads();

    // ---- stage Wr [256 x 256] -> int8 in two halves; lane keeps 4 quarter-rows ----
    int4 wr[16];   // wr[i*4+r] = Wr[obase+i][q*64 + r*16 .. +15]
    {
        const float4* wr4 = (const float4*)Wr;
        // half A: rows 0..127 (8192 dwords)
        #pragma unroll
        for (int it = 0; it < 32; ++it) {
            int flat = it * 256 + tid;
            wstage[flat] = qpack4(wr4[flat], 8.0f, -8.0f, 7.0f);
        }
        __syncthreads();
        if (obase < 128) {
            const int4* p = (const int4*)wstage;  // row o_local = 16 int4s
            #pragma unroll
            for (int i = 0; i < 4; ++i)
                #pragma unroll
                for (int r = 0; r < 4; ++r)
                    wr[i * 4 + r] = p[(obase + i) * 16 + q * 4 + r];
        }
        __syncthreads();
        // half B: rows 128..255
        #pragma unroll
        for (int it = 0; it < 32; ++it) {
            int flat = it * 256 + tid;
            wstage[flat] = qpack4(wr4[8192 + flat], 8.0f, -8.0f, 7.0f);
        }
        __syncthreads();
        if (obase >= 128) {
            const int4* p = (const int4*)wstage;
            #pragma unroll
            for (int i = 0; i < 4; ++i)
                #pragma unroll
                for (int r = 0; r < 4; ++r)
                    wr[i * 4 + r] = p[(obase - 128 + i) * 16 + q * 4 + r];
        }
        __syncthreads();
    }

    // ---- stage Wo [16 x 256] -> int8, resident in wstage[0..1023] ----
    {
        const float4* wo4 = (const float4*)Wo;
        #pragma unroll
        for (int it = 0; it < 4; ++it) {
            int flat = it * 256 + tid;
            wstage[flat] = qpack4(wo4[flat], 8.0f, -8.0f, 7.0f);
        }
    }

    const float4 bv4 = *(const float4*)(bias + obase);
    const float bvv[4] = {bv4.x, bv4.y, bv4.z, bv4.w};

    // ---- prologue: chunk 0 of x, h0 = 0 ----
    const float4* rowf4 = (const float4*)(x + (size_t)brow * (TSEQ * IDIM));
    {
        float4 xf = rowf4[tid];
        xbuf[0][tid] = qpack4(xf, 128.0f, -128.0f, 127.0f);
        if (tid < 64) hbuf[0][tid] = 0;
    }
    __syncthreads();

    // ---- main recurrence ----
    for (int c = 0; c < NCHUNK; ++c) {
        float4 nf;
        if (c < NCHUNK - 1) nf = rowf4[(c + 1) * 256 + tid];
        const int xb = c & 1;
        const int* xbase = xbuf[xb];

        #pragma unroll
        for (int s = 0; s < CHUNK; ++s) {
            const int pb = s & 1;
            // lane reads only its k-quarter of h: dwords q*16 .. q*16+15
            int4 hh[4];
            {
                const int4* hP = (const int4*)hbuf[pb];
                #pragma unroll
                for (int r = 0; r < 4; ++r) hh[r] = hP[q * 4 + r];
            }
            // x_t quarter: dwords s*16 + q*4 .. +3
            const int4 xx = ((const int4*)(xbase + s * 16))[q];

            int acc[4] = {0, 0, 0, 0};
            #pragma unroll
            for (int r = 0; r < 4; ++r) {
                #pragma unroll
                for (int i = 0; i < 4; ++i) {
                    const int4 wv = wr[i * 4 + r];
                    acc[i] = sdot4i8(hh[r].x, wv.x, acc[i]);
                    acc[i] = sdot4i8(hh[r].y, wv.y, acc[i]);
                    acc[i] = sdot4i8(hh[r].z, wv.z, acc[i]);
                    acc[i] = sdot4i8(hh[r].w, wv.w, acc[i]);
                }
            }
            #pragma unroll
            for (int i = 0; i < 4; ++i) {
                acc[i] = sdot4i8(xx.x, wiq[i].x, acc[i]);
                acc[i] = sdot4i8(xx.y, wiq[i].y, acc[i]);
                acc[i] = sdot4i8(xx.z, wiq[i].z, acc[i]);
                acc[i] = sdot4i8(xx.w, wiq[i].w, acc[i]);
            }

            // quad butterfly: full z for outputs obase..obase+3 in all 4 lanes
            int packed = 0;
            #pragma unroll
            for (int i = 0; i < 4; ++i) {
                const int z = quad_reduce_add(acc[i]);
                // exact modrelu + 8-bit requantize (fp32, matches reference):
                // zf=z/1024 exact; m=relu(|zf|+b); clip(rne(m*128)) with sign
                const float zf = (float)z;
                const float t1 = fmaf(fabsf(zf), 0.0009765625f, bvv[i]);
                const float t2 = fmaxf(t1, 0.0f);
                const float r  = rintf(t2 * 128.0f);
                const float rp = fminf(r, 127.0f);
                const float rn = fminf(r, 128.0f);
                int v = (z < 0) ? -(int)rn : (int)rp;
                v = (z == 0) ? 0 : v;
                packed |= (v & 255) << (8 * i);
            }
            if (q == 0) hbuf[pb ^ 1][w * 16 + m16] = packed;

            if (s == CHUNK - 1 && c < NCHUNK - 1) {
                xbuf[xb ^ 1][tid] = qpack4(nf, 128.0f, -128.0f, 127.0f);
            }
            __syncthreads();
        }
    }

    // ---- epilogue: out[b, o] = h_last . Wo_row(o) / 1024 (h_last in hbuf[0]) ----
    if (tid < ODIM) {
        const int4* wo = (const int4*)wstage;
        const int4* hl = (const int4*)hbuf[0];
        int a0 = 0, a1 = 0, a2 = 0, a3 = 0;
        #pragma unroll
        for (int i = 0; i < 16; ++i) {
            int4 w4 = wo[tid * 16 + i];
            int4 h4 = hl[i];
            a0 = sdot4i8(h4.x, w4.x, a0);
            a1 = sdot4i8(h4.y, w4.y, a1);
            a2 = sdot4i8(h4.z, w4.z, a2);
            a3 = sdot4i8(h4.w, w4.w, a3);
        }
        out[brow * ODIM + tid] = (float)((a0 + a1) + (a2 + a3)) * 0.0009765625f;
    }
}

extern "C" void kernel_launch(void* const* d_in, const int* in_sizes, int n_in,
                              void* d_out, int out_size, void* d_ws, size_t ws_size,
                              hipStream_t stream) {
    const float* x  = (const float*)d_in[0];   // [B, T, I]
    const float* Wi = (const float*)d_in[1];   // [H, I]
    const float* Wr = (const float*)d_in[2];   // [H, H]
    const float* Wo = (const float*)d_in[3];   // [O, H]
    const float* b  = (const float*)d_in[4];   // [H]
    float* out = (float*)d_out;                // [B, O]

    const int B = in_sizes[0] / (TSEQ * IDIM); // 256
    qornn_kernel<<<B, HDIM, 0, stream>>>(x, Wi, Wr, Wo, b, out);
}

// Round 3
// 423.056 us; speedup vs baseline: 1.2218x; 1.2218x over previous
//
#include <hip/hip_runtime.h>

// QORNN: quantized orthogonal RNN — exact-integer recurrence.
// v3: latency-focused. Evidence from r1/r2: bank conflicts and LDS throughput
// are negligible (~1 cy/step); kernel is latency/barrier-bound at 1 wave/SIMD
// (~1100 cy/step vs ~250 cy essential issue). Changes:
//  - whole x row staged to LDS as int8 upfront (64 KB): no global ops in the
//    step loop, so __syncthreads' vmcnt(0) drain is free; no chunk machinery.
//  - lane-specialized modrelu: butterfly-reduce, lane q handles output
//    obase+q only (1 modrelu/lane, not 4), per-lane ds_write_b8 at byte tid.
//  - u_{t+1} = x_{t+1}.Wi prefetch-computed during step t (h-independent ILP
//    that fills the post-barrier LDS read-latency bubble); split dot chains.

#define TSEQ 1024
#define IDIM 64
#define HDIM 256
#define ODIM 16

__device__ __forceinline__ int sdot4i8(int a, int b, int c) {
#if __has_builtin(__builtin_amdgcn_sdot4)
    return __builtin_amdgcn_sdot4(a, b, c, false);
#else
    int r = c;
    r += ((a << 24) >> 24) * ((b << 24) >> 24);
    r += ((a << 16) >> 24) * ((b << 16) >> 24);
    r += ((a << 8)  >> 24) * ((b << 8)  >> 24);
    r += (a >> 24) * (b >> 24);
    return r;
#endif
}

__device__ __forceinline__ int qpack4(float4 f, float s, float lo, float hi) {
    int a = (int)fminf(fmaxf(rintf(f.x * s), lo), hi);
    int b = (int)fminf(fmaxf(rintf(f.y * s), lo), hi);
    int c = (int)fminf(fmaxf(rintf(f.z * s), lo), hi);
    int d = (int)fminf(fmaxf(rintf(f.w * s), lo), hi);
    return (a & 255) | ((b & 255) << 8) | ((c & 255) << 16) | ((d & 255) << 24);
}

// quad butterfly sum: all 4 lanes of each quad end with the quad-sum
__device__ __forceinline__ int qsum(int v) {
    v += __builtin_amdgcn_update_dpp(0, v, 0xB1, 0xF, 0xF, true); // quad_perm xor1
    v += __builtin_amdgcn_update_dpp(0, v, 0x4E, 0xF, 0xF, true); // quad_perm xor2
    return v;
}

__global__ __launch_bounds__(256, 1)
void qornn_kernel(const float* __restrict__ x, const float* __restrict__ Wi,
                  const float* __restrict__ Wr, const float* __restrict__ Wo,
                  const float* __restrict__ bias, float* __restrict__ out) {
    __shared__ alignas(16) int xlds[TSEQ * 16 + 16]; // whole row, int8-packed (64KB + pad)
    __shared__ alignas(16) int wstage[8192];         // 32 KB staging; Wo resident after init
    __shared__ alignas(16) int hbuf[2][64];          // double-buffered h (256 int8 each)

    const int tid = threadIdx.x;
    const int brow = blockIdx.x;
    const int w    = tid >> 6;          // wave 0..3
    const int l    = tid & 63;
    const int q    = l & 3;             // k-quarter this lane reads; also its output slot
    const int m16  = l >> 2;            // quad id in wave
    const int obase = w * 64 + m16 * 4; // outputs obase..obase+3 (obase+q == tid)

    // ---- stage Wi [256 x 64] fp32 -> int8 (scale 8); lane keeps 4 quarter-rows ----
    {
        const float4* wi4 = (const float4*)Wi;
        #pragma unroll
        for (int it = 0; it < 16; ++it) {
            int flat = it * 256 + tid;
            wstage[flat] = qpack4(wi4[flat], 8.0f, -8.0f, 7.0f);
        }
    }
    __syncthreads();
    int4 wiq[4];   // wiq[i] = Wi[obase+i][q*16 .. q*16+15]
    {
        const int4* p = (const int4*)wstage;
        #pragma unroll
        for (int i = 0; i < 4; ++i) wiq[i] = p[(obase + i) * 4 + q];
    }
    __syncthreads();

    // ---- stage Wr [256 x 256] -> int8 in two halves; lane keeps 4 quarter-rows ----
    int4 wr[16];   // wr[i*4+r] = Wr[obase+i][q*64 + r*16 .. +15]
    {
        const float4* wr4 = (const float4*)Wr;
        #pragma unroll
        for (int it = 0; it < 32; ++it) {
            int flat = it * 256 + tid;
            wstage[flat] = qpack4(wr4[flat], 8.0f, -8.0f, 7.0f);
        }
        __syncthreads();
        if (obase < 128) {
            const int4* p = (const int4*)wstage;
            #pragma unroll
            for (int i = 0; i < 4; ++i)
                #pragma unroll
                for (int r = 0; r < 4; ++r)
                    wr[i * 4 + r] = p[(obase + i) * 16 + q * 4 + r];
        }
        __syncthreads();
        #pragma unroll
        for (int it = 0; it < 32; ++it) {
            int flat = it * 256 + tid;
            wstage[flat] = qpack4(wr4[8192 + flat], 8.0f, -8.0f, 7.0f);
        }
        __syncthreads();
        if (obase >= 128) {
            const int4* p = (const int4*)wstage;
            #pragma unroll
            for (int i = 0; i < 4; ++i)
                #pragma unroll
                for (int r = 0; r < 4; ++r)
                    wr[i * 4 + r] = p[(obase - 128 + i) * 16 + q * 4 + r];
        }
        __syncthreads();
    }

    // ---- stage Wo [16 x 256] -> int8, resident in wstage[0..1023] ----
    {
        const float4* wo4 = (const float4*)Wo;
        #pragma unroll
        for (int it = 0; it < 4; ++it) {
            int flat = it * 256 + tid;
            wstage[flat] = qpack4(wo4[flat], 8.0f, -8.0f, 7.0f);
        }
    }

    // ---- stage entire x row to LDS as int8 (scale 128) ----
    {
        const float4* rowf4 = (const float4*)(x + (size_t)brow * (TSEQ * IDIM));
        #pragma unroll 8
        for (int it = 0; it < 64; ++it) {
            int flat = it * 256 + tid;               // float4 idx == packed dword idx
            xlds[flat] = qpack4(rowf4[flat], 128.0f, -128.0f, 127.0f);
        }
    }
    if (tid < 64) hbuf[0][tid] = 0;                  // h0 = 0
    __syncthreads();

    const float bv = bias[tid];                      // bias for output tid (== obase+q)
    const bool qb0 = (q & 1) != 0;
    const bool qb1 = (q & 2) != 0;

    // u accumulators for t=0 (x_t . Wi quarter-rows)
    int u[4];
    {
        const int4 xx = ((const int4*)xlds)[q];
        #pragma unroll
        for (int i = 0; i < 4; ++i) {
            int s = sdot4i8(xx.x, wiq[i].x, 0);
            s = sdot4i8(xx.y, wiq[i].y, s);
            s = sdot4i8(xx.z, wiq[i].z, s);
            u[i] = sdot4i8(xx.w, wiq[i].w, s);
        }
    }

    // ---- main recurrence: 1024 steps, no global traffic, 1 barrier/step ----
    #pragma unroll 2
    for (int t = 0; t < TSEQ; ++t) {
        // read this lane's k-quarter of h_t
        int4 hh[4];
        {
            const int4* hP = (const int4*)hbuf[t & 1];
            #pragma unroll
            for (int r = 0; r < 4; ++r) hh[r] = hP[q * 4 + r];
        }
        // prefetch next x quarter (xlds padded so t=1023 read is safe)
        const int4 xn = ((const int4*)xlds)[(t + 1) * 4 + q];

        // z partials: two chains per output, seeded with u[i]
        int za[4], zb[4];
        #pragma unroll
        for (int i = 0; i < 4; ++i) {
            int s0 = u[i];
            s0 = sdot4i8(hh[0].x, wr[i * 4 + 0].x, s0);
            s0 = sdot4i8(hh[0].y, wr[i * 4 + 0].y, s0);
            s0 = sdot4i8(hh[0].z, wr[i * 4 + 0].z, s0);
            s0 = sdot4i8(hh[0].w, wr[i * 4 + 0].w, s0);
            s0 = sdot4i8(hh[1].x, wr[i * 4 + 1].x, s0);
            s0 = sdot4i8(hh[1].y, wr[i * 4 + 1].y, s0);
            s0 = sdot4i8(hh[1].z, wr[i * 4 + 1].z, s0);
            s0 = sdot4i8(hh[1].w, wr[i * 4 + 1].w, s0);
            int s1 = 0;
            s1 = sdot4i8(hh[2].x, wr[i * 4 + 2].x, s1);
            s1 = sdot4i8(hh[2].y, wr[i * 4 + 2].y, s1);
            s1 = sdot4i8(hh[2].z, wr[i * 4 + 2].z, s1);
            s1 = sdot4i8(hh[2].w, wr[i * 4 + 2].w, s1);
            s1 = sdot4i8(hh[3].x, wr[i * 4 + 3].x, s1);
            s1 = sdot4i8(hh[3].y, wr[i * 4 + 3].y, s1);
            s1 = sdot4i8(hh[3].z, wr[i * 4 + 3].z, s1);
            s1 = sdot4i8(hh[3].w, wr[i * 4 + 3].w, s1);
            za[i] = s0; zb[i] = s1;
        }
        // u for step t+1 (independent of h -> fills latency bubbles)
        int un[4];
        #pragma unroll
        for (int i = 0; i < 4; ++i) {
            int s = sdot4i8(xn.x, wiq[i].x, 0);
            s = sdot4i8(xn.y, wiq[i].y, s);
            s = sdot4i8(xn.z, wiq[i].z, s);
            un[i] = sdot4i8(xn.w, wiq[i].w, s);
        }

        // quad-reduce all 4 outputs, then lane q keeps output obase+q only
        const int z0 = qsum(za[0] + zb[0]);
        const int z1 = qsum(za[1] + zb[1]);
        const int z2 = qsum(za[2] + zb[2]);
        const int z3 = qsum(za[3] + zb[3]);
        const int zlo = qb0 ? z1 : z0;
        const int zhi = qb0 ? z3 : z2;
        const int z   = qb1 ? zhi : zlo;

        // exact modrelu + 8-bit requantize (fp32 rounding identical to ref)
        const float zf = (float)z;
        const float t1 = fmaf(fabsf(zf), 0.0009765625f, bv);
        const float t2 = fmaxf(t1, 0.0f);
        const float r  = rintf(t2 * 128.0f);
        const int vpos = (int)fminf(r, 127.0f);
        const int vneg = -(int)fminf(r, 128.0f);
        int hv = (z < 0) ? vneg : vpos;
        hv = (z == 0) ? 0 : hv;

        ((signed char*)hbuf[(t + 1) & 1])[tid] = (signed char)hv;

        #pragma unroll
        for (int i = 0; i < 4; ++i) u[i] = un[i];
        __syncthreads();
    }

    // ---- epilogue: out[b, o] = h_last . Wo_row(o) / 1024  (h_1024 in hbuf[0]) ----
    if (tid < ODIM) {
        const int4* wo = (const int4*)wstage;
        const int4* hl = (const int4*)hbuf[0];
        int a0 = 0, a1 = 0, a2 = 0, a3 = 0;
        #pragma unroll
        for (int i = 0; i < 16; ++i) {
            int4 w4 = wo[tid * 16 + i];
            int4 h4 = hl[i];
            a0 = sdot4i8(h4.x, w4.x, a0);
            a1 = sdot4i8(h4.y, w4.y, a1);
            a2 = sdot4i8(h4.z, w4.z, a2);
            a3 = sdot4i8(h4.w, w4.w, a3);
        }
        out[brow * ODIM + tid] = (float)((a0 + a1) + (a2 + a3)) * 0.0009765625f;
    }
}

extern "C" void kernel_launch(void* const* d_in, const int* in_sizes, int n_in,
                              void* d_out, int out_size, void* d_ws, size_t ws_size,
                              hipStream_t stream) {
    const float* x  = (const float*)d_in[0];   // [B, T, I]
    const float* Wi = (const float*)d_in[1];   // [H, I]
    const float* Wr = (const float*)d_in[2];   // [H, H]
    const float* Wo = (const float*)d_in[3];   // [O, H]
    const float* b  = (const float*)d_in[4];   // [H]
    float* out = (float*)d_out;                // [B, O]

    const int B = in_sizes[0] / (TSEQ * IDIM); // 256
    qornn_kernel<<<B, HDIM, 0, stream>>>(x, Wi, Wr, Wo, b, out);
}